// Round 9
// baseline (229.551 us; speedup 1.0000x reference)
//
#include <hip/hip_runtime.h>
#include <hip/hip_fp16.h>

// ---------------------------------------------------------------------------
// ReconGNN: out = conv(relu(conv(x@W1^T)+b1) @ W2^T) + b2
// R23: (1) gemm2 FUSED into conv64: h1b was consumed only by gemm2; conv64
// groups now write their 64 post-ReLU fp16 features (same rounding -> bit-
// identical) to a 4KB swizzled LDS tile; after one barrier waves 0/2 run the
// exact gemm2 MFMA (32 nodes x 40 out x K=64, 6 MFMA/wave) + identical int8
// epilogue writing h2 directly. Removes a dispatch + 25.6MB HBM round-trip.
// (2) k_prep binfill chunk 4096->2048: LDS union 28.7->16.4KB (gemm1's
// size), 5->9 blocks/CU, grid 1173->1564 (>1 residency round -> overlap).
// Pipeline: memset -> k_prep{binfill || gemm1} -> degscat(scan + bucket-
//   ordered scatter + sc1*=dis) -> conv64g2(conv+gemm2) -> conv40
// ---------------------------------------------------------------------------

typedef __attribute__((ext_vector_type(8))) _Float16 half8v;
typedef __attribute__((ext_vector_type(4))) float   float4v;

// ---- binfill body: bucket edges by destination bin (c>>8), 2048/block ----
// record = src | (c&255)<<17   (N <= 131072). Inline int64/int32 detection.
__device__ __forceinline__ void binfill_body(char* smem, const int* __restrict__ ed,
                                             int* __restrict__ gbincnt,
                                             unsigned* __restrict__ binbuf,
                                             int E, int cap, int bid) {
  int*            hist   = (int*)smem;                        // 2 KB
  int*            cursor = hist + 512;                        // 2 KB
  unsigned*       rec    = (unsigned*)(cursor + 512);         // 8 KB
  unsigned short* binv   = (unsigned short*)(rec + 2048);     // 4 KB
  int*            s_is64 = (int*)(binv + 2048);               // 4 B
  int t = threadIdx.x;
  hist[t] = 0; hist[t + 256] = 0;
  if (t == 0) *s_is64 = 1;
  __syncthreads();
  {   // same sample in every block -> same decision (L2-hot after block 0)
    int any = 0;
    #pragma unroll
    for (int u = 0; u < 8; ++u) {
      int idx = 2 * (t * 8 + u) + 1;          // odd words 1..4095
      if (idx < 2 * E && ed[idx] != 0) any = 1;
    }
    if (any) *s_is64 = 0;                     // benign race
  }
  __syncthreads();
  const int is64 = *s_is64;
  const int base = bid * 2048;
  const int nE = min(2048, E - base);
  for (int j = t; j < nE; j += 256) {
    int e = base + j;
    int r = is64 ? ed[2 * e] : ed[e];
    int c = is64 ? ed[2 * (E + e)] : ed[E + e];
    rec[j] = (unsigned)r | ((unsigned)(c & 255) << 17);
    binv[j] = (unsigned short)(c >> 8);
    atomicAdd(&hist[c >> 8], 1);
  }
  __syncthreads();
  for (int b = t; b < 512; b += 256) {
    int h = hist[b];
    cursor[b] = h ? atomicAdd(&gbincnt[b], h) : 0;
  }
  __syncthreads();
  for (int j = t; j < nE; j += 256) {
    int bin = binv[j];
    int pos = atomicAdd(&cursor[bin], 1);
    if (pos < cap)
      binbuf[(size_t)bin * cap + pos] = rec[j];
  }
}

// ---- gemm1 body (MFMA f16): h1 rows = int8(X[N][128] @ W[64][128]^T),
//      sc1raw[row] = rowmax/127 (NO dis; degscat folds dis in afterwards).
//      X direct global->reg; W in LDS fp16 swizzled. ----
__device__ __forceinline__ void gemm1_body(char* smem, const float* __restrict__ X,
                                           const float* __restrict__ W,
                                           unsigned char* __restrict__ h1q,
                                           float* __restrict__ sc1, int N, int bid) {
  _Float16* wl = (_Float16*)smem;      // 16 KB
  const int t = threadIdx.x;
  const int row0 = bid * 128;
  const int w = t >> 6, l = t & 63;
  const int m0 = w * 32;
  const int lr = l & 15, q = l >> 4;

  // issue all X fragment loads first: 16 independent float4 HBM streams.
  float4 xr[4][2][2];   // [kc][mt][half]
  #pragma unroll
  for (int kc = 0; kc < 4; ++kc) {
    #pragma unroll
    for (int mt = 0; mt < 2; ++mt) {
      int row = min(row0 + m0 + mt * 16 + lr, N - 1);   // clamp: OOB rows read
      const float* p = &X[(size_t)row * 128 + kc * 32 + q * 8];  // valid mem,
      xr[kc][mt][0] = *(const float4*)p;                // masked at epilogue
      xr[kc][mt][1] = *(const float4*)(p + 4);
    }
  }

  // stage W (64x128) to LDS fp16, swizzled (reused by every wave)
  #pragma unroll
  for (int j = 0; j < 8; ++j) {
    int qq = t + 256 * j;
    int r = qq >> 5, k4 = qq & 31;
    float4 v = *(const float4*)&W[(size_t)r * 128 + k4 * 4];
    _Float16 h4[4] = {(_Float16)v.x, (_Float16)v.y, (_Float16)v.z, (_Float16)v.w};
    int k = (k4 * 4) ^ ((r & 7) * 8);
    *(float2*)&wl[r * 128 + k] = *(float2*)h4;
  }
  __syncthreads();

  float4v acc[2][4] = {};
  #pragma unroll
  for (int kc = 0; kc < 4; ++kc) {
    half8v a[2], b[4];
    #pragma unroll
    for (int mt = 0; mt < 2; ++mt) {
      float4 v0 = xr[kc][mt][0], v1 = xr[kc][mt][1];
      _Float16 h8[8] = {(_Float16)v0.x, (_Float16)v0.y, (_Float16)v0.z, (_Float16)v0.w,
                        (_Float16)v1.x, (_Float16)v1.y, (_Float16)v1.z, (_Float16)v1.w};
      a[mt] = *(half8v*)h8;
    }
    #pragma unroll
    for (int nt = 0; nt < 4; ++nt) {
      int n = nt * 16 + lr;
      int k = (kc * 32 + q * 8) ^ ((n & 7) * 8);
      b[nt] = *(half8v*)&wl[n * 128 + k];
    }
    #pragma unroll
    for (int mt = 0; mt < 2; ++mt)
      #pragma unroll
      for (int nt = 0; nt < 4; ++nt)
        acc[mt][nt] = __builtin_amdgcn_mfma_f32_16x16x32_f16(a[mt], b[nt], acc[mt][nt], 0, 0, 0);
  }

  // epilogue: per row (16-lane group, same q) reduce rowmax, quantize int8.
  #pragma unroll
  for (int mt = 0; mt < 2; ++mt) {
    #pragma unroll
    for (int r = 0; r < 4; ++r) {
      int row = row0 + m0 + mt * 16 + q * 4 + r;
      if (row < N) {                         // uniform within 16-lane group
        float v0 = acc[mt][0][r];
        float v1 = acc[mt][1][r];
        float v2 = acc[mt][2][r];
        float v3 = acc[mt][3][r];
        float m = fmaxf(fmaxf(fabsf(v0), fabsf(v1)), fmaxf(fabsf(v2), fabsf(v3)));
        #pragma unroll
        for (int off = 1; off < 16; off <<= 1)
          m = fmaxf(m, __shfl_xor(m, off));   // stays within 16-lane group
        float inv = (m > 0.f) ? (127.f / m) : 0.f;
        unsigned char* dst = h1q + (size_t)row * 64;
        int q0 = (int)rintf(v0 * inv);
        int q1 = (int)rintf(v1 * inv);
        int q2 = (int)rintf(v2 * inv);
        int q3 = (int)rintf(v3 * inv);
        q0 = max(-127, min(127, q0));
        q1 = max(-127, min(127, q1));
        q2 = max(-127, min(127, q2));
        q3 = max(-127, min(127, q3));
        dst[lr]      = (unsigned char)(signed char)q0;
        dst[lr + 16] = (unsigned char)(signed char)q1;
        dst[lr + 32] = (unsigned char)(signed char)q2;
        dst[lr + 48] = (unsigned char)(signed char)q3;
        if (lr == 0) sc1[row] = m * (1.f / 127.f);
      }
    }
  }
}

// ---- mega-kernel: blocks [0,FB) binfill, [FB,FB+MB) gemm1 (independent) ----
__launch_bounds__(256)
__global__ void k_prep(const int* __restrict__ ed, int* __restrict__ gbincnt,
                       unsigned* __restrict__ binbuf, int E, int cap,
                       const float* __restrict__ X, const float* __restrict__ W,
                       unsigned char* __restrict__ h1q, float* __restrict__ sc1,
                       int N, int FB) {
  __shared__ __align__(16) char smem[16512];
  if (blockIdx.x < FB)
    binfill_body(smem, ed, gbincnt, binbuf, E, cap, blockIdx.x);
  else
    gemm1_body(smem, X, W, h1q, sc1, N, blockIdx.x - FB);
}

// ---- fused: bin-count prefix + per-bin degree/scan -> dis/rowptr, scatter
//      srcs in 8-bucket source-range order (L2 residency), sc1 *= dis. ----
__global__ void k_degscat(const unsigned* __restrict__ binbuf, const int* __restrict__ gbincnt,
                          float* __restrict__ dis, int* __restrict__ rowptr,
                          int* __restrict__ srcs, float* __restrict__ sc1,
                          int NBINS, int N, int cap) {
  __shared__ int sd[512];          // global bin-count prefix (2 KB)
  __shared__ int cnt[256];         // degree (1 KB)
  __shared__ int sc[256];          // degree scan (1 KB)
  __shared__ int bc[256][8];       // per-node per-src-bucket count->cursor (8 KB)
  __shared__ unsigned rec[8192];   // 32 KB
  int t = threadIdx.x, b = blockIdx.x;
  sd[t]       = (t < NBINS)       ? min(gbincnt[t], cap)       : 0;
  sd[t + 256] = (t + 256 < NBINS) ? min(gbincnt[t + 256], cap) : 0;
  cnt[t] = 0;
  #pragma unroll
  for (int k = 0; k < 8; ++k) bc[t][k] = 0;
  __syncthreads();
  for (int off = 1; off < 512; off <<= 1) {
    int v0 = (t >= off) ? sd[t - off] : 0;
    int v1 = sd[t + 256 - off];
    __syncthreads();
    sd[t] += v0; sd[t + 256] += v1;
    __syncthreads();
  }
  const int mybase = (b == 0) ? 0 : sd[b - 1];
  if (b == NBINS - 1 && t == 0) rowptr[N] = sd[NBINS - 1];

  int n = min(gbincnt[b], cap);
  const unsigned* buf = binbuf + (size_t)b * cap;
  for (int j = t; j < n; j += 256) {
    unsigned v = buf[j];
    rec[j] = v;
    atomicAdd(&cnt[v >> 17], 1);
    atomicAdd(&bc[v >> 17][(v & 0x1FFFF) >> 14], 1);   // src bucket (1MB slice)
  }
  __syncthreads();
  sc[t] = cnt[t];
  __syncthreads();
  for (int off = 1; off < 256; off <<= 1) {
    int v = (t >= off) ? sc[t - off] : 0;
    __syncthreads();
    sc[t] += v;
    __syncthreads();
  }
  int rp = mybase + ((t == 0) ? 0 : sc[t - 1]);
  int node = b * 256 + t;
  if (node < N) {
    int d = cnt[t];
    float dv = (d > 0) ? rsqrtf((float)d) : 0.f;
    dis[node] = dv;
    rowptr[node] = rp;
    sc1[node] *= dv;                 // fold dest-row norm into the conv scale
  }
  // per-node prefix over the 8 src-buckets -> bucket cursors
  {
    int base2 = rp;
    #pragma unroll
    for (int k = 0; k < 8; ++k) {
      int c = bc[t][k];
      bc[t][k] = base2;
      base2 += c;
    }
  }
  __syncthreads();
  for (int j = t; j < n; j += 256) {
    unsigned v = rec[j];
    int pos = atomicAdd(&bc[v >> 17][(v & 0x1FFFF) >> 14], 1);
    srcs[pos] = (int)(v & 0x1FFFF);
  }
}

// ---- conv1 + gemm2 fused: 8 lanes/node conv (int8+sc1, 1 line/edge,
//      8-edge unroll, src-bucket ordered) -> post-ReLU fp16 row into 4KB
//      swizzled LDS tile -> one barrier -> waves 0/2 run gemm2's MFMA
//      (32 nodes x 48 out x K=64) + identical int8+scale epilogue to h2. ----
__launch_bounds__(256)
__global__ void k_conv64g2(const unsigned char* __restrict__ H, const float* __restrict__ sc1,
                           const int* __restrict__ rowptr, const int* __restrict__ srcs,
                           const float* __restrict__ dis, const float* __restrict__ b1,
                           const float* __restrict__ W2, unsigned char* __restrict__ h2,
                           int N) {
  __shared__ _Float16 xl[32 * 64];   // 4 KB: block's 32 post-ReLU rows, swizzled
  __shared__ _Float16 wl[48 * 64];   // 6 KB: W2 zero-padded rows 40..47
  int t = threadIdx.x;

  // stage W2 (40x64 -> 48x64) swizzled, exactly as the old gemm2
  for (int i = t; i < 48 * 8; i += 256) {
    int c = i >> 3, kq = i & 7;
    _Float16 h8w[8];
    #pragma unroll
    for (int j = 0; j < 8; ++j)
      h8w[j] = (c < 40) ? (_Float16)W2[c * 64 + kq * 8 + j] : (_Float16)0.f;
    *(float4*)&wl[c * 64 + ((kq * 8) ^ ((c & 7) * 8))] = *(float4*)h8w;
  }

  int li = t & 7;
  int r = t >> 3;                        // local node 0..31
  int node = blockIdx.x * 32 + r;
  float a0 = 0.f, a1 = 0.f, a2 = 0.f, a3 = 0.f,
        a4 = 0.f, a5 = 0.f, a6 = 0.f, a7 = 0.f;
  if (node < N) {
    int s = rowptr[node], e = rowptr[node + 1];
    int last = e - 1;
    for (int p = s; p < e; p += 8) {
      int sv[8]; uint2 rv[8]; float cv[8];
      #pragma unroll
      for (int u = 0; u < 8; ++u) sv[u] = srcs[min(p + u, last)];
      #pragma unroll
      for (int u = 0; u < 8; ++u) rv[u] = *(const uint2*)&H[(size_t)sv[u] * 64 + 8 * li];
      #pragma unroll
      for (int u = 0; u < 8; ++u) cv[u] = sc1[sv[u]];
      #pragma unroll
      for (int u = 0; u < 8; ++u) {
        if (p + u < e) {
          int x0 = (int)rv[u].x, x1 = (int)rv[u].y;
          float c = cv[u];
          a0 = fmaf((float)((x0 << 24) >> 24), c, a0);
          a1 = fmaf((float)((x0 << 16) >> 24), c, a1);
          a2 = fmaf((float)((x0 << 8)  >> 24), c, a2);
          a3 = fmaf((float)( x0        >> 24), c, a3);
          a4 = fmaf((float)((x1 << 24) >> 24), c, a4);
          a5 = fmaf((float)((x1 << 16) >> 24), c, a5);
          a6 = fmaf((float)((x1 << 8)  >> 24), c, a6);
          a7 = fmaf((float)( x1        >> 24), c, a7);
        }
      }
    }
  }
  // post-ReLU fp16 row into swizzled LDS (zeros for OOB nodes)
  {
    _Float16 h8[8] = {};
    if (node < N) {
      float dn = dis[node];
      const float* bb = b1 + 8 * li;
      h8[0] = (_Float16)fmaxf(fmaf(a0, dn, bb[0]), 0.f);
      h8[1] = (_Float16)fmaxf(fmaf(a1, dn, bb[1]), 0.f);
      h8[2] = (_Float16)fmaxf(fmaf(a2, dn, bb[2]), 0.f);
      h8[3] = (_Float16)fmaxf(fmaf(a3, dn, bb[3]), 0.f);
      h8[4] = (_Float16)fmaxf(fmaf(a4, dn, bb[4]), 0.f);
      h8[5] = (_Float16)fmaxf(fmaf(a5, dn, bb[5]), 0.f);
      h8[6] = (_Float16)fmaxf(fmaf(a6, dn, bb[6]), 0.f);
      h8[7] = (_Float16)fmaxf(fmaf(a7, dn, bb[7]), 0.f);
    }
    *(float4*)&xl[r * 64 + ((li * 8) ^ ((r & 7) * 8))] = *(float4*)h8;
  }
  __syncthreads();

  // gemm2 phase: waves 0 and 2 each handle one 16-row M-tile
  int w = t >> 6, l = t & 63;
  if ((w & 1) == 0) {
    int tile = w >> 1;                   // 0 or 1
    int lr = l & 15, q = l >> 4;
    float4v acc[3] = {};
    #pragma unroll
    for (int kc = 0; kc < 2; ++kc) {
      int m = tile * 16 + lr;
      int ka = (kc * 32 + q * 8) ^ ((m & 7) * 8);
      half8v a = *(half8v*)&xl[m * 64 + ka];
      #pragma unroll
      for (int nt = 0; nt < 3; ++nt) {
        int n = nt * 16 + lr;
        int kb = (kc * 32 + q * 8) ^ ((n & 7) * 8);
        half8v bfr = *(half8v*)&wl[n * 64 + kb];
        acc[nt] = __builtin_amdgcn_mfma_f32_16x16x32_f16(a, bfr, acc[nt], 0, 0, 0);
      }
    }
    // identical epilogue to the old gemm2 (16-lane-group rowmax, int8+scale)
    #pragma unroll
    for (int r2 = 0; r2 < 4; ++r2) {
      int row = blockIdx.x * 32 + tile * 16 + q * 4 + r2;
      if (row < N) {
        float dr = dis[row];
        float v0 = acc[0][r2] * dr;
        float v1 = acc[1][r2] * dr;
        float v2 = acc[2][r2] * dr;
        float m = fmaxf(fabsf(v0), fmaxf(fabsf(v1), fabsf(v2)));
        #pragma unroll
        for (int off = 1; off < 16; off <<= 1)
          m = fmaxf(m, __shfl_xor(m, off));   // stays within 16-lane group
        float s = m * (1.f / 127.f);
        float inv = (m > 0.f) ? (127.f / m) : 0.f;
        unsigned char* dst = h2 + (size_t)row * 64;
        int q0 = (int)rintf(v0 * inv);
        int q1 = (int)rintf(v1 * inv);
        int q2 = (int)rintf(v2 * inv);
        q0 = max(-127, min(127, q0));
        q1 = max(-127, min(127, q1));
        q2 = max(-127, min(127, q2));
        dst[lr]      = (unsigned char)(signed char)q0;
        dst[lr + 16] = (unsigned char)(signed char)q1;
        if (lr + 32 < 40) dst[lr + 32] = (unsigned char)(signed char)q2;
        if (lr == 0) *(float*)&dst[40] = s;
        if (lr >= 1 && lr <= 5) *(int*)&dst[40 + 4 * lr] = 0;   // bytes 44..63
      }
    }
  }
}

// ---- conv2 (int8+scale in, 64B rows = 1 line/edge; fp32 out): 8 lanes per
//      node, lanes li<5 own features 8li..8li+7, scale from same cache line.
//      8-edge unroll; src-bucket ordered edge lists. ----
__launch_bounds__(256)
__global__ void k_conv40(const unsigned char* __restrict__ H, const int* __restrict__ rowptr,
                         const int* __restrict__ srcs, const float* __restrict__ dis,
                         const float* __restrict__ b2, float* __restrict__ out, int N) {
  int t = threadIdx.x;
  int li = t & 7;
  int node = blockIdx.x * 32 + (t >> 3);
  if (node >= N) return;                 // group-uniform
  bool act = li < 5;
  int s = rowptr[node], e = rowptr[node + 1];
  int last = e - 1;
  float a0 = 0.f, a1 = 0.f, a2 = 0.f, a3 = 0.f,
        a4 = 0.f, a5 = 0.f, a6 = 0.f, a7 = 0.f;
  for (int p = s; p < e; p += 8) {
    int sv[8];
    #pragma unroll
    for (int u = 0; u < 8; ++u) sv[u] = srcs[min(p + u, last)];
    if (act) {
      uint2 rv[8]; float cv[8];
      #pragma unroll
      for (int u = 0; u < 8; ++u)
        rv[u] = *(const uint2*)&H[(size_t)sv[u] * 64 + 8 * li];
      #pragma unroll
      for (int u = 0; u < 8; ++u)
        cv[u] = *(const float*)&H[(size_t)sv[u] * 64 + 40];   // same cache line
      #pragma unroll
      for (int u = 0; u < 8; ++u) {
        if (p + u < e) {
          int x0 = (int)rv[u].x, x1 = (int)rv[u].y;
          float c = cv[u];
          a0 = fmaf((float)((x0 << 24) >> 24), c, a0);
          a1 = fmaf((float)((x0 << 16) >> 24), c, a1);
          a2 = fmaf((float)((x0 << 8)  >> 24), c, a2);
          a3 = fmaf((float)( x0        >> 24), c, a3);
          a4 = fmaf((float)((x1 << 24) >> 24), c, a4);
          a5 = fmaf((float)((x1 << 16) >> 24), c, a5);
          a6 = fmaf((float)((x1 << 8)  >> 24), c, a6);
          a7 = fmaf((float)( x1        >> 24), c, a7);
        }
      }
    }
  }
  if (act) {                             // features 8*li..8*li+7 (0..39)
    float dn = dis[node];
    const float* bb = b2 + 8 * li;
    float4 v0 = make_float4(fmaf(a0, dn, bb[0]), fmaf(a1, dn, bb[1]),
                            fmaf(a2, dn, bb[2]), fmaf(a3, dn, bb[3]));
    float4 v1 = make_float4(fmaf(a4, dn, bb[4]), fmaf(a5, dn, bb[5]),
                            fmaf(a6, dn, bb[6]), fmaf(a7, dn, bb[7]));
    *(float4*)&out[(size_t)node * 40 + 8 * li] = v0;
    *(float4*)&out[(size_t)node * 40 + 8 * li + 4] = v1;
  }
}

extern "C" void kernel_launch(void* const* d_in, const int* in_sizes, int n_in,
                              void* d_out, int out_size, void* d_ws, size_t ws_size,
                              hipStream_t stream) {
  const float* x  = (const float*)d_in[0];
  const int*   ed = (const int*)d_in[1];
  const float* W1 = (const float*)d_in[2];
  const float* b1 = (const float*)d_in[3];
  const float* W2 = (const float*)d_in[4];
  const float* b2 = (const float*)d_in[5];
  float* out = (float*)d_out;

  const int FIN = 128;
  const int N = in_sizes[0] / FIN;
  const int E = in_sizes[1] / 2;
  const int NBINS = (N + 255) >> 8;              // 391 (<=512)
  const int cap = 8192;                          // mean bin load ~4092

  char* ws = (char*)d_ws;
  size_t off = 0;
  auto alloc = [&](size_t bytes) {
    void* p = ws + off;
    off = (off + bytes + 255) & ~(size_t)255;
    return p;
  };
  int*           gbincnt = (int*)alloc(512 * 4);
  float*         dis     = (float*)alloc((size_t)N * 4);
  int*           rowptr  = (int*)alloc(((size_t)N + 1) * 4);
  int*           srcs    = (int*)alloc((size_t)E * 4);
  unsigned*      binbuf  = (unsigned*)alloc((size_t)NBINS * cap * 4);  // 12.8 MB
  unsigned char* h1q     = (unsigned char*)alloc((size_t)N * 64);      // int8 rows
  float*         sc1     = (float*)alloc((size_t)N * 4);
  unsigned char* h2      = (unsigned char*)alloc((size_t)N * 64);      // int8+scale

  hipMemsetAsync(gbincnt, 0, 512 * 4, stream);

  int fb = (E + 2047) / 2048;
  int mb = (N + 127) / 128;
  int cb = (N + 31) / 32;
  k_prep<<<fb + mb, 256, 0, stream>>>(ed, gbincnt, binbuf, E, cap, x, W1, h1q, sc1, N, fb);
  k_degscat<<<NBINS, 256, 0, stream>>>(binbuf, gbincnt, dis, rowptr, srcs, sc1,
                                       NBINS, N, cap);
  k_conv64g2<<<cb, 256, 0, stream>>>(h1q, sc1, rowptr, srcs, dis, b1, W2, h2, N);
  k_conv40<<<cb, 256, 0, stream>>>(h2, rowptr, srcs, dis, b2, out, N);
}

// Round 10
// 209.547 us; speedup vs baseline: 1.0955x; 1.0955x over previous
//
#include <hip/hip_runtime.h>
#include <hip/hip_fp16.h>

// ---------------------------------------------------------------------------
// ReconGNN: out = conv(relu(conv(x@W1^T)+b1) @ W2^T) + b2
// R24: R23 FULLY REVERTED (both changes regressed: gemm2-fusion = sum not
// max due to the pre-MFMA barrier waiting on max-degree conv groups; binfill
// chunk 2048 raised contention). Back to R22 (208.9us best) with ONE change:
// k_prep block roles are Bresenham-INTERLEAVED (binfill spread evenly
// through the grid) instead of contiguous-split. R22 counters showed occ 15%
// ~= one residency round -> contiguous split makes early CUs all scatter-
// bound and late CUs all latency-bound; interleaving mixes both types per
// CU so their stalls overlap.
// Pipeline: memset -> k_prep{binfill || gemm1, interleaved} -> degscat(scan
//   + bucket-ordered scatter + sc1*=dis) -> conv64 -> gemm2 -> conv40
// ---------------------------------------------------------------------------

typedef __attribute__((ext_vector_type(8))) _Float16 half8v;
typedef __attribute__((ext_vector_type(4))) float   float4v;

// ---- binfill body: bucket edges by destination bin (c>>8), 4096/block ----
// record = src | (c&255)<<17   (N <= 131072). Inline int64/int32 detection.
__device__ __forceinline__ void binfill_body(char* smem, const int* __restrict__ ed,
                                             int* __restrict__ gbincnt,
                                             unsigned* __restrict__ binbuf,
                                             int E, int cap, int bid) {
  int*            hist   = (int*)smem;                        // 2 KB
  int*            cursor = hist + 512;                        // 2 KB
  unsigned*       rec    = (unsigned*)(cursor + 512);         // 16 KB
  unsigned short* binv   = (unsigned short*)(rec + 4096);     // 8 KB
  int*            s_is64 = (int*)(binv + 4096);               // 4 B
  int t = threadIdx.x;
  hist[t] = 0; hist[t + 256] = 0;
  if (t == 0) *s_is64 = 1;
  __syncthreads();
  {   // same sample in every block -> same decision (L2-hot after block 0)
    int any = 0;
    #pragma unroll
    for (int u = 0; u < 8; ++u) {
      int idx = 2 * (t * 8 + u) + 1;          // odd words 1..4095
      if (idx < 2 * E && ed[idx] != 0) any = 1;
    }
    if (any) *s_is64 = 0;                     // benign race
  }
  __syncthreads();
  const int is64 = *s_is64;
  const int base = bid * 4096;
  const int nE = min(4096, E - base);
  for (int j = t; j < nE; j += 256) {
    int e = base + j;
    int r = is64 ? ed[2 * e] : ed[e];
    int c = is64 ? ed[2 * (E + e)] : ed[E + e];
    rec[j] = (unsigned)r | ((unsigned)(c & 255) << 17);
    binv[j] = (unsigned short)(c >> 8);
    atomicAdd(&hist[c >> 8], 1);
  }
  __syncthreads();
  for (int b = t; b < 512; b += 256) {
    int h = hist[b];
    cursor[b] = h ? atomicAdd(&gbincnt[b], h) : 0;
  }
  __syncthreads();
  for (int j = t; j < nE; j += 256) {
    int bin = binv[j];
    int pos = atomicAdd(&cursor[bin], 1);
    if (pos < cap)
      binbuf[(size_t)bin * cap + pos] = rec[j];
  }
}

// ---- gemm1 body (MFMA f16): h1 rows = int8(X[N][128] @ W[64][128]^T),
//      sc1raw[row] = rowmax/127 (NO dis; degscat folds dis in afterwards).
//      X direct global->reg; W in LDS fp16 swizzled. ----
__device__ __forceinline__ void gemm1_body(char* smem, const float* __restrict__ X,
                                           const float* __restrict__ W,
                                           unsigned char* __restrict__ h1q,
                                           float* __restrict__ sc1, int N, int bid) {
  _Float16* wl = (_Float16*)smem;      // 16 KB
  const int t = threadIdx.x;
  const int row0 = bid * 128;
  const int w = t >> 6, l = t & 63;
  const int m0 = w * 32;
  const int lr = l & 15, q = l >> 4;

  // issue all X fragment loads first: 16 independent float4 HBM streams.
  float4 xr[4][2][2];   // [kc][mt][half]
  #pragma unroll
  for (int kc = 0; kc < 4; ++kc) {
    #pragma unroll
    for (int mt = 0; mt < 2; ++mt) {
      int row = min(row0 + m0 + mt * 16 + lr, N - 1);   // clamp: OOB rows read
      const float* p = &X[(size_t)row * 128 + kc * 32 + q * 8];  // valid mem,
      xr[kc][mt][0] = *(const float4*)p;                // masked at epilogue
      xr[kc][mt][1] = *(const float4*)(p + 4);
    }
  }

  // stage W (64x128) to LDS fp16, swizzled (reused by every wave)
  #pragma unroll
  for (int j = 0; j < 8; ++j) {
    int qq = t + 256 * j;
    int r = qq >> 5, k4 = qq & 31;
    float4 v = *(const float4*)&W[(size_t)r * 128 + k4 * 4];
    _Float16 h4[4] = {(_Float16)v.x, (_Float16)v.y, (_Float16)v.z, (_Float16)v.w};
    int k = (k4 * 4) ^ ((r & 7) * 8);
    *(float2*)&wl[r * 128 + k] = *(float2*)h4;
  }
  __syncthreads();

  float4v acc[2][4] = {};
  #pragma unroll
  for (int kc = 0; kc < 4; ++kc) {
    half8v a[2], b[4];
    #pragma unroll
    for (int mt = 0; mt < 2; ++mt) {
      float4 v0 = xr[kc][mt][0], v1 = xr[kc][mt][1];
      _Float16 h8[8] = {(_Float16)v0.x, (_Float16)v0.y, (_Float16)v0.z, (_Float16)v0.w,
                        (_Float16)v1.x, (_Float16)v1.y, (_Float16)v1.z, (_Float16)v1.w};
      a[mt] = *(half8v*)h8;
    }
    #pragma unroll
    for (int nt = 0; nt < 4; ++nt) {
      int n = nt * 16 + lr;
      int k = (kc * 32 + q * 8) ^ ((n & 7) * 8);
      b[nt] = *(half8v*)&wl[n * 128 + k];
    }
    #pragma unroll
    for (int mt = 0; mt < 2; ++mt)
      #pragma unroll
      for (int nt = 0; nt < 4; ++nt)
        acc[mt][nt] = __builtin_amdgcn_mfma_f32_16x16x32_f16(a[mt], b[nt], acc[mt][nt], 0, 0, 0);
  }

  // epilogue: per row (16-lane group, same q) reduce rowmax, quantize int8.
  #pragma unroll
  for (int mt = 0; mt < 2; ++mt) {
    #pragma unroll
    for (int r = 0; r < 4; ++r) {
      int row = row0 + m0 + mt * 16 + q * 4 + r;
      if (row < N) {                         // uniform within 16-lane group
        float v0 = acc[mt][0][r];
        float v1 = acc[mt][1][r];
        float v2 = acc[mt][2][r];
        float v3 = acc[mt][3][r];
        float m = fmaxf(fmaxf(fabsf(v0), fabsf(v1)), fmaxf(fabsf(v2), fabsf(v3)));
        #pragma unroll
        for (int off = 1; off < 16; off <<= 1)
          m = fmaxf(m, __shfl_xor(m, off));   // stays within 16-lane group
        float inv = (m > 0.f) ? (127.f / m) : 0.f;
        unsigned char* dst = h1q + (size_t)row * 64;
        int q0 = (int)rintf(v0 * inv);
        int q1 = (int)rintf(v1 * inv);
        int q2 = (int)rintf(v2 * inv);
        int q3 = (int)rintf(v3 * inv);
        q0 = max(-127, min(127, q0));
        q1 = max(-127, min(127, q1));
        q2 = max(-127, min(127, q2));
        q3 = max(-127, min(127, q3));
        dst[lr]      = (unsigned char)(signed char)q0;
        dst[lr + 16] = (unsigned char)(signed char)q1;
        dst[lr + 32] = (unsigned char)(signed char)q2;
        dst[lr + 48] = (unsigned char)(signed char)q3;
        if (lr == 0) sc1[row] = m * (1.f / 127.f);
      }
    }
  }
}

// ---- mega-kernel: FB binfill + MB gemm1 blocks, Bresenham-interleaved so
//      every CU hosts a mix of scatter-bound and latency-bound blocks. ----
__launch_bounds__(256)
__global__ void k_prep(const int* __restrict__ ed, int* __restrict__ gbincnt,
                       unsigned* __restrict__ binbuf, int E, int cap,
                       const float* __restrict__ X, const float* __restrict__ W,
                       unsigned char* __restrict__ h1q, float* __restrict__ sc1,
                       int N, int FB, int TOT) {
  __shared__ __align__(16) char smem[28680];
  long long bid = blockIdx.x;
  long long lo = (bid * FB) / TOT;
  long long hi = ((bid + 1) * FB) / TOT;
  if (hi > lo)                             // this slot is a binfill block
    binfill_body(smem, ed, gbincnt, binbuf, E, cap, (int)lo);
  else                                     // gemm1 block; rank among gemm1s
    gemm1_body(smem, X, W, h1q, sc1, N, (int)(bid - lo));
}

// ---- fused: bin-count prefix + per-bin degree/scan -> dis/rowptr, scatter
//      srcs in 8-bucket source-range order (L2 residency), sc1 *= dis. ----
__global__ void k_degscat(const unsigned* __restrict__ binbuf, const int* __restrict__ gbincnt,
                          float* __restrict__ dis, int* __restrict__ rowptr,
                          int* __restrict__ srcs, float* __restrict__ sc1,
                          int NBINS, int N, int cap) {
  __shared__ int sd[512];          // global bin-count prefix (2 KB)
  __shared__ int cnt[256];         // degree (1 KB)
  __shared__ int sc[256];          // degree scan (1 KB)
  __shared__ int bc[256][8];       // per-node per-src-bucket count->cursor (8 KB)
  __shared__ unsigned rec[8192];   // 32 KB
  int t = threadIdx.x, b = blockIdx.x;
  sd[t]       = (t < NBINS)       ? min(gbincnt[t], cap)       : 0;
  sd[t + 256] = (t + 256 < NBINS) ? min(gbincnt[t + 256], cap) : 0;
  cnt[t] = 0;
  #pragma unroll
  for (int k = 0; k < 8; ++k) bc[t][k] = 0;
  __syncthreads();
  for (int off = 1; off < 512; off <<= 1) {
    int v0 = (t >= off) ? sd[t - off] : 0;
    int v1 = sd[t + 256 - off];
    __syncthreads();
    sd[t] += v0; sd[t + 256] += v1;
    __syncthreads();
  }
  const int mybase = (b == 0) ? 0 : sd[b - 1];
  if (b == NBINS - 1 && t == 0) rowptr[N] = sd[NBINS - 1];

  int n = min(gbincnt[b], cap);
  const unsigned* buf = binbuf + (size_t)b * cap;
  for (int j = t; j < n; j += 256) {
    unsigned v = buf[j];
    rec[j] = v;
    atomicAdd(&cnt[v >> 17], 1);
    atomicAdd(&bc[v >> 17][(v & 0x1FFFF) >> 14], 1);   // src bucket (1MB slice)
  }
  __syncthreads();
  sc[t] = cnt[t];
  __syncthreads();
  for (int off = 1; off < 256; off <<= 1) {
    int v = (t >= off) ? sc[t - off] : 0;
    __syncthreads();
    sc[t] += v;
    __syncthreads();
  }
  int rp = mybase + ((t == 0) ? 0 : sc[t - 1]);
  int node = b * 256 + t;
  if (node < N) {
    int d = cnt[t];
    float dv = (d > 0) ? rsqrtf((float)d) : 0.f;
    dis[node] = dv;
    rowptr[node] = rp;
    sc1[node] *= dv;                 // fold dest-row norm into the conv scale
  }
  // per-node prefix over the 8 src-buckets -> bucket cursors
  {
    int base2 = rp;
    #pragma unroll
    for (int k = 0; k < 8; ++k) {
      int c = bc[t][k];
      bc[t][k] = base2;
      base2 += c;
    }
  }
  __syncthreads();
  for (int j = t; j < n; j += 256) {
    unsigned v = rec[j];
    int pos = atomicAdd(&bc[v >> 17][(v & 0x1FFFF) >> 14], 1);
    srcs[pos] = (int)(v & 0x1FFFF);
  }
}

// ---- gemm2 (MFMA f16): h2 rows = int8((h1b @ W2^T)*dis) + per-row scale ----
// row layout (64B): bytes 0..39 int8 features, 40..43 fp32 scale, 44..63 zero.
__launch_bounds__(256)
__global__ void k_gemm2_mfma(const __half* __restrict__ Xh, const float* __restrict__ W,
                             const float* __restrict__ dis, unsigned char* __restrict__ h2,
                             int N) {
  __shared__ _Float16 xl[128 * 64];   // 16 KB
  __shared__ _Float16 wl[48 * 64];    // 6 KB (rows 40..47 zero)
  const int t = threadIdx.x;
  const int row0 = blockIdx.x * 128;

  for (int i = t; i < 48 * 8; i += 256) {
    int c = i >> 3, kq = i & 7;
    _Float16 h8[8];
    #pragma unroll
    for (int j = 0; j < 8; ++j)
      h8[j] = (c < 40) ? (_Float16)W[c * 64 + kq * 8 + j] : (_Float16)0.f;
    *(float4*)&wl[c * 64 + ((kq * 8) ^ ((c & 7) * 8))] = *(float4*)h8;
  }
  for (int i = t; i < 1024; i += 256) {
    int r = i >> 3, kq = i & 7;
    int row = row0 + r;
    float4 v = make_float4(0.f, 0.f, 0.f, 0.f);
    if (row < N) v = *(const float4*)&Xh[(size_t)row * 64 + kq * 8];
    *(float4*)&xl[r * 64 + ((kq * 8) ^ ((r & 7) * 8))] = v;
  }
  __syncthreads();

  const int w = t >> 6, l = t & 63;
  const int m0 = w * 32;
  const int lr = l & 15, q = l >> 4;

  float4v acc[2][3] = {};
  #pragma unroll
  for (int kc = 0; kc < 2; ++kc) {
    half8v a[2], b[3];
    #pragma unroll
    for (int mt = 0; mt < 2; ++mt) {
      int m = m0 + mt * 16 + lr;
      int k = (kc * 32 + q * 8) ^ ((m & 7) * 8);
      a[mt] = *(half8v*)&xl[m * 64 + k];
    }
    #pragma unroll
    for (int nt = 0; nt < 3; ++nt) {
      int n = nt * 16 + lr;
      int k = (kc * 32 + q * 8) ^ ((n & 7) * 8);
      b[nt] = *(half8v*)&wl[n * 64 + k];
    }
    #pragma unroll
    for (int mt = 0; mt < 2; ++mt)
      #pragma unroll
      for (int nt = 0; nt < 3; ++nt)
        acc[mt][nt] = __builtin_amdgcn_mfma_f32_16x16x32_f16(a[mt], b[nt], acc[mt][nt], 0, 0, 0);
  }

  // epilogue: per row (16-lane group, same q) reduce rowmax, quantize int8.
  // cols 40..47 are zero (W zero-padded) so including them is safe.
  #pragma unroll
  for (int mt = 0; mt < 2; ++mt) {
    #pragma unroll
    for (int r = 0; r < 4; ++r) {
      int row = row0 + m0 + mt * 16 + q * 4 + r;
      if (row < N) {
        float dr = dis[row];
        float v0 = acc[mt][0][r] * dr;
        float v1 = acc[mt][1][r] * dr;
        float v2 = acc[mt][2][r] * dr;
        float m = fmaxf(fabsf(v0), fmaxf(fabsf(v1), fabsf(v2)));
        #pragma unroll
        for (int off = 1; off < 16; off <<= 1)
          m = fmaxf(m, __shfl_xor(m, off));     // stays within 16-lane group
        float s = m * (1.f / 127.f);
        float inv = (m > 0.f) ? (127.f / m) : 0.f;
        unsigned char* dst = h2 + (size_t)row * 64;
        int q0 = (int)rintf(v0 * inv);
        int q1 = (int)rintf(v1 * inv);
        int q2 = (int)rintf(v2 * inv);
        q0 = max(-127, min(127, q0));
        q1 = max(-127, min(127, q1));
        q2 = max(-127, min(127, q2));
        dst[lr]      = (unsigned char)(signed char)q0;
        dst[lr + 16] = (unsigned char)(signed char)q1;
        if (lr + 32 < 40) dst[lr + 32] = (unsigned char)(signed char)q2;
        if (lr == 0) *(float*)&dst[40] = s;
        if (lr >= 1 && lr <= 5) *(int*)&dst[40 + 4 * lr] = 0;   // bytes 44..63
      }
    }
  }
}

// ---- conv1 (D=64, int8+sc1 in = 1 line/edge): 8 lanes per node, lane li
//      owns features 8li..8li+7. srcs via L1 broadcast, NO shuffles, no
//      reduction. 8-edge unroll; edge list is src-bucket ordered (L2). ----
__launch_bounds__(256)
__global__ void k_conv64(const unsigned char* __restrict__ H, const float* __restrict__ sc1,
                         const int* __restrict__ rowptr, const int* __restrict__ srcs,
                         const float* __restrict__ dis, const float* __restrict__ b1,
                         __half* __restrict__ out, int N) {
  int t = threadIdx.x;
  int li = t & 7;
  int node = blockIdx.x * 32 + (t >> 3);
  if (node >= N) return;                 // group-uniform (8-lane groups)
  int s = rowptr[node], e = rowptr[node + 1];
  int last = e - 1;
  float a0 = 0.f, a1 = 0.f, a2 = 0.f, a3 = 0.f,
        a4 = 0.f, a5 = 0.f, a6 = 0.f, a7 = 0.f;
  for (int p = s; p < e; p += 8) {
    int sv[8]; uint2 rv[8]; float cv[8];
    #pragma unroll
    for (int u = 0; u < 8; ++u) sv[u] = srcs[min(p + u, last)];
    #pragma unroll
    for (int u = 0; u < 8; ++u) rv[u] = *(const uint2*)&H[(size_t)sv[u] * 64 + 8 * li];
    #pragma unroll
    for (int u = 0; u < 8; ++u) cv[u] = sc1[sv[u]];
    #pragma unroll
    for (int u = 0; u < 8; ++u) {
      if (p + u < e) {
        int x0 = (int)rv[u].x, x1 = (int)rv[u].y;
        float c = cv[u];
        a0 = fmaf((float)((x0 << 24) >> 24), c, a0);
        a1 = fmaf((float)((x0 << 16) >> 24), c, a1);
        a2 = fmaf((float)((x0 << 8)  >> 24), c, a2);
        a3 = fmaf((float)( x0        >> 24), c, a3);
        a4 = fmaf((float)((x1 << 24) >> 24), c, a4);
        a5 = fmaf((float)((x1 << 16) >> 24), c, a5);
        a6 = fmaf((float)((x1 << 8)  >> 24), c, a6);
        a7 = fmaf((float)( x1        >> 24), c, a7);
      }
    }
  }
  float dn = dis[node];
  const float* bb = b1 + 8 * li;
  __half hv[8];
  hv[0] = __float2half_rn(fmaxf(fmaf(a0, dn, bb[0]), 0.f));
  hv[1] = __float2half_rn(fmaxf(fmaf(a1, dn, bb[1]), 0.f));
  hv[2] = __float2half_rn(fmaxf(fmaf(a2, dn, bb[2]), 0.f));
  hv[3] = __float2half_rn(fmaxf(fmaf(a3, dn, bb[3]), 0.f));
  hv[4] = __float2half_rn(fmaxf(fmaf(a4, dn, bb[4]), 0.f));
  hv[5] = __float2half_rn(fmaxf(fmaf(a5, dn, bb[5]), 0.f));
  hv[6] = __float2half_rn(fmaxf(fmaf(a6, dn, bb[6]), 0.f));
  hv[7] = __float2half_rn(fmaxf(fmaf(a7, dn, bb[7]), 0.f));
  *(float4*)&out[(size_t)node * 64 + 8 * li] = *(float4*)hv;
}

// ---- conv2 (int8+scale in, 64B rows = 1 line/edge; fp32 out): 8 lanes per
//      node, lanes li<5 own features 8li..8li+7, scale from same cache line.
//      8-edge unroll; src-bucket ordered edge lists. ----
__launch_bounds__(256)
__global__ void k_conv40(const unsigned char* __restrict__ H, const int* __restrict__ rowptr,
                         const int* __restrict__ srcs, const float* __restrict__ dis,
                         const float* __restrict__ b2, float* __restrict__ out, int N) {
  int t = threadIdx.x;
  int li = t & 7;
  int node = blockIdx.x * 32 + (t >> 3);
  if (node >= N) return;                 // group-uniform
  bool act = li < 5;
  int s = rowptr[node], e = rowptr[node + 1];
  int last = e - 1;
  float a0 = 0.f, a1 = 0.f, a2 = 0.f, a3 = 0.f,
        a4 = 0.f, a5 = 0.f, a6 = 0.f, a7 = 0.f;
  for (int p = s; p < e; p += 8) {
    int sv[8];
    #pragma unroll
    for (int u = 0; u < 8; ++u) sv[u] = srcs[min(p + u, last)];
    if (act) {
      uint2 rv[8]; float cv[8];
      #pragma unroll
      for (int u = 0; u < 8; ++u)
        rv[u] = *(const uint2*)&H[(size_t)sv[u] * 64 + 8 * li];
      #pragma unroll
      for (int u = 0; u < 8; ++u)
        cv[u] = *(const float*)&H[(size_t)sv[u] * 64 + 40];   // same cache line
      #pragma unroll
      for (int u = 0; u < 8; ++u) {
        if (p + u < e) {
          int x0 = (int)rv[u].x, x1 = (int)rv[u].y;
          float c = cv[u];
          a0 = fmaf((float)((x0 << 24) >> 24), c, a0);
          a1 = fmaf((float)((x0 << 16) >> 24), c, a1);
          a2 = fmaf((float)((x0 << 8)  >> 24), c, a2);
          a3 = fmaf((float)( x0        >> 24), c, a3);
          a4 = fmaf((float)((x1 << 24) >> 24), c, a4);
          a5 = fmaf((float)((x1 << 16) >> 24), c, a5);
          a6 = fmaf((float)((x1 << 8)  >> 24), c, a6);
          a7 = fmaf((float)( x1        >> 24), c, a7);
        }
      }
    }
  }
  if (act) {                             // features 8*li..8*li+7 (0..39)
    float dn = dis[node];
    const float* bb = b2 + 8 * li;
    float4 v0 = make_float4(fmaf(a0, dn, bb[0]), fmaf(a1, dn, bb[1]),
                            fmaf(a2, dn, bb[2]), fmaf(a3, dn, bb[3]));
    float4 v1 = make_float4(fmaf(a4, dn, bb[4]), fmaf(a5, dn, bb[5]),
                            fmaf(a6, dn, bb[6]), fmaf(a7, dn, bb[7]));
    *(float4*)&out[(size_t)node * 40 + 8 * li] = v0;
    *(float4*)&out[(size_t)node * 40 + 8 * li + 4] = v1;
  }
}

extern "C" void kernel_launch(void* const* d_in, const int* in_sizes, int n_in,
                              void* d_out, int out_size, void* d_ws, size_t ws_size,
                              hipStream_t stream) {
  const float* x  = (const float*)d_in[0];
  const int*   ed = (const int*)d_in[1];
  const float* W1 = (const float*)d_in[2];
  const float* b1 = (const float*)d_in[3];
  const float* W2 = (const float*)d_in[4];
  const float* b2 = (const float*)d_in[5];
  float* out = (float*)d_out;

  const int FIN = 128, FH = 64;
  const int N = in_sizes[0] / FIN;
  const int E = in_sizes[1] / 2;
  const int NBINS = (N + 255) >> 8;              // 391 (<=512)
  const int cap = 8192;                          // mean bin load ~4092

  char* ws = (char*)d_ws;
  size_t off = 0;
  auto alloc = [&](size_t bytes) {
    void* p = ws + off;
    off = (off + bytes + 255) & ~(size_t)255;
    return p;
  };
  int*           gbincnt = (int*)alloc(512 * 4);
  float*         dis     = (float*)alloc((size_t)N * 4);
  int*           rowptr  = (int*)alloc(((size_t)N + 1) * 4);
  int*           srcs    = (int*)alloc((size_t)E * 4);
  unsigned*      binbuf  = (unsigned*)alloc((size_t)NBINS * cap * 4);  // 12.8 MB
  unsigned char* h1q     = (unsigned char*)alloc((size_t)N * 64);      // int8 rows
  float*         sc1     = (float*)alloc((size_t)N * 4);
  __half*        h1b     = (__half*)alloc((size_t)N * FH * 2);         // conv1 out
  unsigned char* h2      = (unsigned char*)alloc((size_t)N * 64);      // int8+scale

  hipMemsetAsync(gbincnt, 0, 512 * 4, stream);

  int fb = (E + 4095) / 4096;
  int mb = (N + 127) / 128;
  int cb = (N + 31) / 32;
  k_prep<<<fb + mb, 256, 0, stream>>>(ed, gbincnt, binbuf, E, cap, x, W1, h1q, sc1,
                                      N, fb, fb + mb);
  k_degscat<<<NBINS, 256, 0, stream>>>(binbuf, gbincnt, dis, rowptr, srcs, sc1,
                                       NBINS, N, cap);
  k_conv64<<<cb, 256, 0, stream>>>(h1q, sc1, rowptr, srcs, dis, b1, h1b, N);
  k_gemm2_mfma<<<mb, 256, 0, stream>>>(h1b, W2, dis, h2, N);
  k_conv40<<<cb, 256, 0, stream>>>(h2, rowptr, srcs, dis, b2, out, N);
}